// Round 1
// baseline (1832.107 us; speedup 1.0000x reference)
//
#include <hip/hip_runtime.h>
#include <math.h>

#define BLK 64
#define LN_EPS 1e-5f

// ---------- helpers ----------

// LayerNorm (over D) + affine + ReLU, result stored to this thread's LDS slot.
template<int D>
__device__ __forceinline__ void ln_relu_store(const float* __restrict__ acc,
                                              const float* __restrict__ g,
                                              const float* __restrict__ b,
                                              float* __restrict__ hme) {
  float m = 0.f;
#pragma unroll
  for (int j = 0; j < D; ++j) m += acc[j];
  m *= (1.0f / D);
  float v = 0.f;
#pragma unroll
  for (int j = 0; j < D; ++j) { float d = acc[j] - m; v = fmaf(d, d, v); }
  v *= (1.0f / D);
  float rs = rsqrtf(v + LN_EPS);
#pragma unroll
  for (int j = 0; j < D; ++j) {
    float h = fmaf((acc[j] - m) * rs, g[j], b[j]);
    hme[j] = fmaxf(h, 0.f);
  }
}

// o[OUT] = hme[IN] @ W[IN][OUT]; h comes from per-thread LDS slot (runtime i
// loop keeps code small; weights are wave-uniform -> scalar loads).
template<int IN, int OUT>
__device__ __forceinline__ void gemv_from_lds(const float* __restrict__ hme,
                                              const float* __restrict__ W,
                                              float* __restrict__ o) {
#pragma unroll
  for (int j = 0; j < OUT; ++j) o[j] = 0.f;
#pragma unroll 4
  for (int i = 0; i < IN; ++i) {
    float hv = hme[i];
#pragma unroll
    for (int j = 0; j < OUT; ++j) o[j] = fmaf(hv, W[i * OUT + j], o[j]);
  }
}

// acc[64] = x[128] @ W[128][64], x streamed from global (row-major, L1-cached)
__device__ __forceinline__ void gemv128_acc(const float* __restrict__ xr,
                                            const float* __restrict__ W,
                                            float* __restrict__ acc) {
#pragma unroll
  for (int j = 0; j < 64; ++j) acc[j] = 0.f;
#pragma unroll 1
  for (int ic = 0; ic < 16; ++ic) {
    float4 a  = *reinterpret_cast<const float4*>(xr + ic * 8);
    float4 bq = *reinterpret_cast<const float4*>(xr + ic * 8 + 4);
    float xv[8] = {a.x, a.y, a.z, a.w, bq.x, bq.y, bq.z, bq.w};
#pragma unroll
    for (int ii = 0; ii < 8; ++ii) {
#pragma unroll
      for (int j = 0; j < 64; ++j)
        acc[j] = fmaf(xv[ii], W[(ic * 8 + ii) * 64 + j], acc[j]);
    }
  }
}

// ---------- fused kernel: one thread = one row ----------

__global__ __launch_bounds__(BLK, 2)
void approach_fused_kernel(
    const float* __restrict__ rep, const float* __restrict__ par,
    const float* __restrict__ kW1, const float* __restrict__ kg1, const float* __restrict__ kb1,
    const float* __restrict__ kW2, const float* __restrict__ kb2,
    const float* __restrict__ qW1, const float* __restrict__ qg1, const float* __restrict__ qb1,
    const float* __restrict__ qW2, const float* __restrict__ qb2,
    const float* __restrict__ vW1, const float* __restrict__ vg1, const float* __restrict__ vb1,
    const float* __restrict__ vW2, const float* __restrict__ vb2,
    const float* __restrict__ aW1, const float* __restrict__ ag1, const float* __restrict__ ab1,
    const float* __restrict__ aW2, const float* __restrict__ ab2,
    const float* __restrict__ rW1, const float* __restrict__ rg1, const float* __restrict__ rb1,
    const float* __restrict__ rW2, const float* __restrict__ rg2, const float* __restrict__ rb2,
    const float* __restrict__ rW3, const float* __restrict__ rb3,
    const float* __restrict__ gW1, const float* __restrict__ gg1, const float* __restrict__ gb1,
    const float* __restrict__ gW2, const float* __restrict__ gb2,
    float* __restrict__ out, int N)
{
  // per-thread LDS scratch, stride 65 -> bank (tid+i)%32, 2-way across wave64 = free
  __shared__ float hbuf[BLK][65];
  const int tid = threadIdx.x;
  const long long row = (long long)blockIdx.x * BLK + tid;
  if (row >= N) return;

  const float* xr = rep + (size_t)row * 128;
  const float p0 = par[row * 3 + 0];
  const float p1 = par[row * 3 + 1];
  const float p2 = par[row * 3 + 2];
  float* hme = &hbuf[tid][0];

  float acc[64];
  float kk[32], vv[32], qq[32];

  // ---- key tower: 128 -> 64 (LN,ReLU) -> 32 (+bias)
  gemv128_acc(xr, kW1, acc);
  ln_relu_store<64>(acc, kg1, kb1, hme);
  gemv_from_lds<64, 32>(hme, kW2, kk);
#pragma unroll
  for (int j = 0; j < 32; ++j) kk[j] += kb2[j];

  // ---- value tower: 128 -> 64 (LN,ReLU) -> 32 (+bias)
  gemv128_acc(xr, vW1, acc);
  ln_relu_store<64>(acc, vg1, vb1, hme);
  gemv_from_lds<64, 32>(hme, vW2, vv);
#pragma unroll
  for (int j = 0; j < 32; ++j) vv[j] += vb2[j];

  // ---- query tower: 3 -> 16 (LN,ReLU) -> 32 (+bias)
  {
    float aq[16];
#pragma unroll
    for (int j = 0; j < 16; ++j) {
      float t = p0 * qW1[j];
      t = fmaf(p1, qW1[16 + j], t);
      t = fmaf(p2, qW1[32 + j], t);
      aq[j] = t;
    }
    ln_relu_store<16>(aq, qg1, qb1, hme);
    gemv_from_lds<16, 32>(hme, qW2, qq);
#pragma unroll
    for (int j = 0; j < 32; ++j) qq[j] += qb2[j];
  }

  // ---- attention: softmax(q*k) * v, then 32 -> 32 (LN,ReLU) -> 16 (+bias)
  float a16[16];
  {
    float s[32];
#pragma unroll
    for (int j = 0; j < 32; ++j) s[j] = qq[j] * kk[j];
    float mx = s[0];
#pragma unroll
    for (int j = 1; j < 32; ++j) mx = fmaxf(mx, s[j]);
    float sum = 0.f;
#pragma unroll
    for (int j = 0; j < 32; ++j) { float e = __expf(s[j] - mx); s[j] = e; sum += e; }
    float inv = 1.0f / sum;
#pragma unroll
    for (int j = 0; j < 32; ++j) hme[j] = s[j] * inv * vv[j];

    float h32[32];
    gemv_from_lds<32, 32>(hme, aW1, h32);
    ln_relu_store<32>(h32, ag1, ab1, hme);
    gemv_from_lds<32, 16>(hme, aW2, a16);
#pragma unroll
    for (int j = 0; j < 16; ++j) a16[j] += ab2[j];
  }

  // ---- residuals tower: 131 -> 64 (LN,ReLU) -> 32 (LN,ReLU) -> 16 (+bias)
  float r16[16];
  {
    gemv128_acc(xr, rW1, acc);
#pragma unroll
    for (int j = 0; j < 64; ++j) {
      float t = acc[j];
      t = fmaf(p0, rW1[128 * 64 + j], t);
      t = fmaf(p1, rW1[129 * 64 + j], t);
      t = fmaf(p2, rW1[130 * 64 + j], t);
      acc[j] = t;
    }
    ln_relu_store<64>(acc, rg1, rb1, hme);
    float r32[32];
    gemv_from_lds<64, 32>(hme, rW2, r32);          // no bias before LN
    ln_relu_store<32>(r32, rg2, rb2, hme);
    gemv_from_lds<32, 16>(hme, rW3, r16);
#pragma unroll
    for (int j = 0; j < 16; ++j) r16[j] += rb3[j];
  }

  // ---- get_approach tower: concat(att,res)[32] -> 16 (LN,ReLU) -> 3 (+bias)
#pragma unroll
  for (int j = 0; j < 16; ++j) hme[j] = a16[j];
#pragma unroll
  for (int j = 0; j < 16; ++j) hme[16 + j] = r16[j];
  {
    float f16[16];
    gemv_from_lds<32, 16>(hme, gW1, f16);
    ln_relu_store<16>(f16, gg1, gb1, hme);
    float o3[3];
    gemv_from_lds<16, 3>(hme, gW2, o3);
#pragma unroll
    for (int c = 0; c < 3; ++c) out[row * 3 + c] = o3[c] + gb2[c];
  }
}

// ---------- launch ----------

extern "C" void kernel_launch(void* const* d_in, const int* in_sizes, int n_in,
                              void* d_out, int out_size, void* d_ws, size_t ws_size,
                              hipStream_t stream) {
  const float* rep = (const float*)d_in[0];
  const float* par = (const float*)d_in[1];
  const float* kW1 = (const float*)d_in[2];
  const float* kg1 = (const float*)d_in[3];
  const float* kb1 = (const float*)d_in[4];
  const float* kW2 = (const float*)d_in[5];
  const float* kb2 = (const float*)d_in[6];
  const float* qW1 = (const float*)d_in[7];
  const float* qg1 = (const float*)d_in[8];
  const float* qb1 = (const float*)d_in[9];
  const float* qW2 = (const float*)d_in[10];
  const float* qb2 = (const float*)d_in[11];
  const float* vW1 = (const float*)d_in[12];
  const float* vg1 = (const float*)d_in[13];
  const float* vb1 = (const float*)d_in[14];
  const float* vW2 = (const float*)d_in[15];
  const float* vb2 = (const float*)d_in[16];
  const float* aW1 = (const float*)d_in[17];
  const float* ag1 = (const float*)d_in[18];
  const float* ab1 = (const float*)d_in[19];
  const float* aW2 = (const float*)d_in[20];
  const float* ab2 = (const float*)d_in[21];
  const float* rW1 = (const float*)d_in[22];
  const float* rg1 = (const float*)d_in[23];
  const float* rb1 = (const float*)d_in[24];
  const float* rW2 = (const float*)d_in[25];
  const float* rg2 = (const float*)d_in[26];
  const float* rb2 = (const float*)d_in[27];
  const float* rW3 = (const float*)d_in[28];
  const float* rb3 = (const float*)d_in[29];
  const float* gW1 = (const float*)d_in[30];
  const float* gg1 = (const float*)d_in[31];
  const float* gb1 = (const float*)d_in[32];
  const float* gW2 = (const float*)d_in[33];
  const float* gb2 = (const float*)d_in[34];

  const int N = in_sizes[0] / 128;
  float* out = (float*)d_out;

  const int grid = (N + BLK - 1) / BLK;
  approach_fused_kernel<<<grid, BLK, 0, stream>>>(
      rep, par,
      kW1, kg1, kb1, kW2, kb2,
      qW1, qg1, qb1, qW2, qb2,
      vW1, vg1, vb1, vW2, vb2,
      aW1, ag1, ab1, aW2, ab2,
      rW1, rg1, rb1, rW2, rg2, rb2, rW3, rb3,
      gW1, gg1, gb1, gW2, gb2,
      out, N);
}

// Round 2
// 1207.965 us; speedup vs baseline: 1.5167x; 1.5167x over previous
//
#include <hip/hip_runtime.h>
#include <math.h>

#define BLK 256
#define LN_EPS 1e-5f

typedef _Float16 half2v __attribute__((ext_vector_type(2)));

// ---------- packed f16 helpers ----------

__device__ __forceinline__ unsigned pkf16(float a, float b) {
  half2v h;
  h[0] = (_Float16)a;
  h[1] = (_Float16)b;
  return __builtin_bit_cast(unsigned, h);
}

__device__ __forceinline__ float dot2f(unsigned hp, unsigned wp, float c) {
  return __builtin_amdgcn_fdot2(__builtin_bit_cast(half2v, hp),
                                __builtin_bit_cast(half2v, wp), c, false);
}

// ---------- ws layout (u32 indices) ----------
#define OFF_KW1 0        // 64x64
#define OFF_VW1 4096     // 64x64
#define OFF_RW1 8192     // 64x64 (first 128 rows of rW1)
#define OFF_KW2 12288    // 32x32
#define OFF_VW2 13312
#define OFF_RW2 14336
#define OFF_AW1 15360    // 16x32
#define OFF_AW2 15872    // 16x16
#define OFF_RW3 16128    // 16x16
#define OFF_GW1 16384    // 16x16
#define OFF_QW2 16640    // 8x32
#define WS_U32_TOTAL 16896

// ---------- prepack kernel: fp32 [IN][OUT] -> packed f16 pairs [IN/2][OUT] ----------

__device__ __forceinline__ void pack_seg(const float* __restrict__ W, int IN2, int OUT,
                                         unsigned* __restrict__ dst, int gtid, int gstride) {
  int tot = IN2 * OUT;
  for (int idx = gtid; idx < tot; idx += gstride) {
    int i2 = idx / OUT;
    int j = idx - i2 * OUT;
    dst[idx] = pkf16(W[(2 * i2) * OUT + j], W[(2 * i2 + 1) * OUT + j]);
  }
}

__global__ void prepack_kernel(const float* kW1, const float* vW1, const float* rW1,
                               const float* kW2, const float* vW2, const float* rW2,
                               const float* aW1, const float* aW2, const float* rW3,
                               const float* gW1, const float* qW2, unsigned* ws) {
  int gtid = blockIdx.x * blockDim.x + threadIdx.x;
  int gstride = gridDim.x * blockDim.x;
  pack_seg(kW1, 64, 64, ws + OFF_KW1, gtid, gstride);
  pack_seg(vW1, 64, 64, ws + OFF_VW1, gtid, gstride);
  pack_seg(rW1, 64, 64, ws + OFF_RW1, gtid, gstride);  // rows 0..127 only
  pack_seg(kW2, 32, 32, ws + OFF_KW2, gtid, gstride);
  pack_seg(vW2, 32, 32, ws + OFF_VW2, gtid, gstride);
  pack_seg(rW2, 32, 32, ws + OFF_RW2, gtid, gstride);
  pack_seg(aW1, 16, 32, ws + OFF_AW1, gtid, gstride);
  pack_seg(aW2, 16, 16, ws + OFF_AW2, gtid, gstride);
  pack_seg(rW3, 16, 16, ws + OFF_RW3, gtid, gstride);
  pack_seg(gW1, 16, 16, ws + OFF_GW1, gtid, gstride);
  pack_seg(qW2, 8, 32, ws + OFF_QW2, gtid, gstride);
}

// ---------- main-kernel helpers ----------

// LayerNorm + affine + ReLU from fp32 acc, store packed f16 pairs to LDS slot.
template<int D>
__device__ __forceinline__ void ln_relu_store_pk(const float* __restrict__ acc,
                                                 const float* __restrict__ g,
                                                 const float* __restrict__ b,
                                                 unsigned* __restrict__ hme) {
  float m = 0.f;
#pragma unroll
  for (int j = 0; j < D; ++j) m += acc[j];
  m *= (1.0f / D);
  float v = 0.f;
#pragma unroll
  for (int j = 0; j < D; ++j) { float d = acc[j] - m; v = fmaf(d, d, v); }
  v *= (1.0f / D);
  float rs = rsqrtf(v + LN_EPS);
#pragma unroll
  for (int j2 = 0; j2 < D / 2; ++j2) {
    float h0 = fmaxf(fmaf((acc[2 * j2] - m) * rs, g[2 * j2], b[2 * j2]), 0.f);
    float h1 = fmaxf(fmaf((acc[2 * j2 + 1] - m) * rs, g[2 * j2 + 1], b[2 * j2 + 1]), 0.f);
    hme[j2] = pkf16(h0, h1);
  }
}

// LayerNorm + affine + ReLU to fp32 registers (for the final tiny tower).
template<int D>
__device__ __forceinline__ void ln_relu_reg(const float* __restrict__ acc,
                                            const float* __restrict__ g,
                                            const float* __restrict__ b,
                                            float* __restrict__ h) {
  float m = 0.f;
#pragma unroll
  for (int j = 0; j < D; ++j) m += acc[j];
  m *= (1.0f / D);
  float v = 0.f;
#pragma unroll
  for (int j = 0; j < D; ++j) { float d = acc[j] - m; v = fmaf(d, d, v); }
  v *= (1.0f / D);
  float rs = rsqrtf(v + LN_EPS);
#pragma unroll
  for (int j = 0; j < D; ++j)
    h[j] = fmaxf(fmaf((acc[j] - m) * rs, g[j], b[j]), 0.f);
}

// o[OUT] = packed-h[IN2 pairs] @ Wp; h from per-thread LDS slot, Wp wave-uniform.
template<int IN2, int OUT>
__device__ __forceinline__ void gemv_pk(const unsigned* __restrict__ hme,
                                        const unsigned* __restrict__ Wp,
                                        float* __restrict__ o) {
#pragma unroll
  for (int j = 0; j < OUT; ++j) o[j] = 0.f;
#pragma unroll 4
  for (int i2 = 0; i2 < IN2; ++i2) {
    unsigned hp = hme[i2];
#pragma unroll
    for (int j = 0; j < OUT; ++j) o[j] = dot2f(hp, Wp[i2 * OUT + j], o[j]);
  }
}

// acc[64] = x[128] @ W; x streamed fp32 from global, converted to f16 pairs.
__device__ __forceinline__ void gemv128_pk(const float* __restrict__ xr,
                                           const unsigned* __restrict__ Wp,
                                           float* __restrict__ acc) {
#pragma unroll
  for (int j = 0; j < 64; ++j) acc[j] = 0.f;
#pragma unroll 1
  for (int ic = 0; ic < 16; ++ic) {
    float4 a = *reinterpret_cast<const float4*>(xr + ic * 8);
    float4 bq = *reinterpret_cast<const float4*>(xr + ic * 8 + 4);
    unsigned xp[4] = {pkf16(a.x, a.y), pkf16(a.z, a.w), pkf16(bq.x, bq.y), pkf16(bq.z, bq.w)};
#pragma unroll
    for (int p = 0; p < 4; ++p) {
#pragma unroll
      for (int j = 0; j < 64; ++j)
        acc[j] = dot2f(xp[p], Wp[(ic * 4 + p) * 64 + j], acc[j]);
    }
  }
}

// ---------- fused kernel: one thread = one row ----------

__global__ __launch_bounds__(BLK, 4)
void approach_fused_pk_kernel(
    const float* __restrict__ rep, const float* __restrict__ par,
    const unsigned* __restrict__ ws,
    const float* __restrict__ kg1, const float* __restrict__ kb1, const float* __restrict__ kb2,
    const float* __restrict__ qW1, const float* __restrict__ qg1, const float* __restrict__ qb1,
    const float* __restrict__ qb2,
    const float* __restrict__ vg1, const float* __restrict__ vb1, const float* __restrict__ vb2,
    const float* __restrict__ ag1, const float* __restrict__ ab1, const float* __restrict__ ab2,
    const float* __restrict__ rW1, const float* __restrict__ rg1, const float* __restrict__ rb1,
    const float* __restrict__ rg2, const float* __restrict__ rb2, const float* __restrict__ rb3,
    const float* __restrict__ gg1, const float* __restrict__ gb1,
    const float* __restrict__ gW2, const float* __restrict__ gb2,
    float* __restrict__ out, int N)
{
  // per-thread packed-f16 LDS slot; stride 33 dwords -> bank (t+i)%32, 2-way = free
  __shared__ unsigned hbuf[BLK][33];
  const int tid = threadIdx.x;
  const long long row = (long long)blockIdx.x * BLK + tid;
  if (row >= N) return;

  const float* xr = rep + (size_t)row * 128;
  const float p0 = par[row * 3 + 0];
  const float p1 = par[row * 3 + 1];
  const float p2 = par[row * 3 + 2];
  unsigned* hme = &hbuf[tid][0];

  float acc[64];
  float kk[32], vv[32], qq[32];

  // ---- key tower: 128 -> 64 (LN,ReLU) -> 32 (+bias)
  gemv128_pk(xr, ws + OFF_KW1, acc);
  ln_relu_store_pk<64>(acc, kg1, kb1, hme);
  gemv_pk<32, 32>(hme, ws + OFF_KW2, kk);
#pragma unroll
  for (int j = 0; j < 32; ++j) kk[j] += kb2[j];

  // ---- value tower
  gemv128_pk(xr, ws + OFF_VW1, acc);
  ln_relu_store_pk<64>(acc, vg1, vb1, hme);
  gemv_pk<32, 32>(hme, ws + OFF_VW2, vv);
#pragma unroll
  for (int j = 0; j < 32; ++j) vv[j] += vb2[j];

  // ---- query tower: 3 -> 16 (LN,ReLU) -> 32 (+bias)   (fp32 first layer, tiny)
  {
    float aq[16];
#pragma unroll
    for (int j = 0; j < 16; ++j) {
      float t = p0 * qW1[j];
      t = fmaf(p1, qW1[16 + j], t);
      t = fmaf(p2, qW1[32 + j], t);
      aq[j] = t;
    }
    ln_relu_store_pk<16>(aq, qg1, qb1, hme);
    gemv_pk<8, 32>(hme, ws + OFF_QW2, qq);
#pragma unroll
    for (int j = 0; j < 32; ++j) qq[j] += qb2[j];
  }

  // ---- attention: softmax(q*k) * v, then 32 -> 32 (LN,ReLU) -> 16 (+bias)
  float a16[16];
  {
    float s[32];
#pragma unroll
    for (int j = 0; j < 32; ++j) s[j] = qq[j] * kk[j];
    float mx = s[0];
#pragma unroll
    for (int j = 1; j < 32; ++j) mx = fmaxf(mx, s[j]);
    float sum = 0.f;
#pragma unroll
    for (int j = 0; j < 32; ++j) { float e = __expf(s[j] - mx); s[j] = e; sum += e; }
    float inv = 1.0f / sum;
#pragma unroll
    for (int j2 = 0; j2 < 16; ++j2)
      hme[j2] = pkf16(s[2 * j2] * inv * vv[2 * j2], s[2 * j2 + 1] * inv * vv[2 * j2 + 1]);

    float h32[32];
    gemv_pk<16, 32>(hme, ws + OFF_AW1, h32);
    ln_relu_store_pk<32>(h32, ag1, ab1, hme);
    gemv_pk<16, 16>(hme, ws + OFF_AW2, a16);
#pragma unroll
    for (int j = 0; j < 16; ++j) a16[j] += ab2[j];
  }

  // ---- residuals tower: 131 -> 64 (LN,ReLU) -> 32 (LN,ReLU) -> 16 (+bias)
  float r16[16];
  {
    gemv128_pk(xr, ws + OFF_RW1, acc);
#pragma unroll
    for (int j = 0; j < 64; ++j) {
      float t = acc[j];
      t = fmaf(p0, rW1[128 * 64 + j], t);
      t = fmaf(p1, rW1[129 * 64 + j], t);
      t = fmaf(p2, rW1[130 * 64 + j], t);
      acc[j] = t;
    }
    ln_relu_store_pk<64>(acc, rg1, rb1, hme);
    float r32[32];
    gemv_pk<32, 32>(hme, ws + OFF_RW2, r32);
    ln_relu_store_pk<32>(r32, rg2, rb2, hme);
    gemv_pk<16, 16>(hme, ws + OFF_RW3, r16);
#pragma unroll
    for (int j = 0; j < 16; ++j) r16[j] += rb3[j];
  }

  // ---- get_approach tower: concat(att,res)[32] -> 16 (LN,ReLU) -> 3 (+bias)
#pragma unroll
  for (int j2 = 0; j2 < 8; ++j2) hme[j2] = pkf16(a16[2 * j2], a16[2 * j2 + 1]);
#pragma unroll
  for (int j2 = 0; j2 < 8; ++j2) hme[8 + j2] = pkf16(r16[2 * j2], r16[2 * j2 + 1]);
  {
    float f16v[16];
    gemv_pk<16, 16>(hme, ws + OFF_GW1, f16v);
    float hg[16];
    ln_relu_reg<16>(f16v, gg1, gb1, hg);
    float o3[3] = {0.f, 0.f, 0.f};
#pragma unroll
    for (int i = 0; i < 16; ++i) {
#pragma unroll
      for (int c = 0; c < 3; ++c) o3[c] = fmaf(hg[i], gW2[i * 3 + c], o3[c]);
    }
#pragma unroll
    for (int c = 0; c < 3; ++c) out[row * 3 + c] = o3[c] + gb2[c];
  }
}

// ---------- fallback: round-1 fp32 kernel (used only if ws too small) ----------

template<int D>
__device__ __forceinline__ void ln_relu_store_f(const float* acc, const float* g,
                                                const float* b, float* hme) {
  float m = 0.f;
#pragma unroll
  for (int j = 0; j < D; ++j) m += acc[j];
  m *= (1.0f / D);
  float v = 0.f;
#pragma unroll
  for (int j = 0; j < D; ++j) { float d = acc[j] - m; v = fmaf(d, d, v); }
  v *= (1.0f / D);
  float rs = rsqrtf(v + LN_EPS);
#pragma unroll
  for (int j = 0; j < D; ++j) hme[j] = fmaxf(fmaf((acc[j] - m) * rs, g[j], b[j]), 0.f);
}

template<int IN, int OUT>
__device__ __forceinline__ void gemv_f(const float* hme, const float* W, float* o) {
#pragma unroll
  for (int j = 0; j < OUT; ++j) o[j] = 0.f;
#pragma unroll 4
  for (int i = 0; i < IN; ++i) {
    float hv = hme[i];
#pragma unroll
    for (int j = 0; j < OUT; ++j) o[j] = fmaf(hv, W[i * OUT + j], o[j]);
  }
}

__device__ __forceinline__ void gemv128_f(const float* xr, const float* W, float* acc) {
#pragma unroll
  for (int j = 0; j < 64; ++j) acc[j] = 0.f;
#pragma unroll 1
  for (int ic = 0; ic < 16; ++ic) {
    float4 a = *reinterpret_cast<const float4*>(xr + ic * 8);
    float4 bq = *reinterpret_cast<const float4*>(xr + ic * 8 + 4);
    float xv[8] = {a.x, a.y, a.z, a.w, bq.x, bq.y, bq.z, bq.w};
#pragma unroll
    for (int ii = 0; ii < 8; ++ii)
#pragma unroll
      for (int j = 0; j < 64; ++j)
        acc[j] = fmaf(xv[ii], W[(ic * 8 + ii) * 64 + j], acc[j]);
  }
}

__global__ __launch_bounds__(64, 2)
void approach_fused_f32_kernel(
    const float* rep, const float* par,
    const float* kW1, const float* kg1, const float* kb1, const float* kW2, const float* kb2,
    const float* qW1, const float* qg1, const float* qb1, const float* qW2, const float* qb2,
    const float* vW1, const float* vg1, const float* vb1, const float* vW2, const float* vb2,
    const float* aW1, const float* ag1, const float* ab1, const float* aW2, const float* ab2,
    const float* rW1, const float* rg1, const float* rb1, const float* rW2, const float* rg2,
    const float* rb2, const float* rW3, const float* rb3,
    const float* gW1, const float* gg1, const float* gb1, const float* gW2, const float* gb2,
    float* out, int N)
{
  __shared__ float hbuf[64][65];
  const int tid = threadIdx.x;
  const long long row = (long long)blockIdx.x * 64 + tid;
  if (row >= N) return;
  const float* xr = rep + (size_t)row * 128;
  const float p0 = par[row * 3 + 0], p1 = par[row * 3 + 1], p2 = par[row * 3 + 2];
  float* hme = &hbuf[tid][0];
  float acc[64], kk[32], vv[32], qq[32];

  gemv128_f(xr, kW1, acc);
  ln_relu_store_f<64>(acc, kg1, kb1, hme);
  gemv_f<64, 32>(hme, kW2, kk);
#pragma unroll
  for (int j = 0; j < 32; ++j) kk[j] += kb2[j];

  gemv128_f(xr, vW1, acc);
  ln_relu_store_f<64>(acc, vg1, vb1, hme);
  gemv_f<64, 32>(hme, vW2, vv);
#pragma unroll
  for (int j = 0; j < 32; ++j) vv[j] += vb2[j];

  {
    float aq[16];
#pragma unroll
    for (int j = 0; j < 16; ++j)
      aq[j] = fmaf(p2, qW1[32 + j], fmaf(p1, qW1[16 + j], p0 * qW1[j]));
    ln_relu_store_f<16>(aq, qg1, qb1, hme);
    gemv_f<16, 32>(hme, qW2, qq);
#pragma unroll
    for (int j = 0; j < 32; ++j) qq[j] += qb2[j];
  }

  float a16[16];
  {
    float s[32];
#pragma unroll
    for (int j = 0; j < 32; ++j) s[j] = qq[j] * kk[j];
    float mx = s[0];
#pragma unroll
    for (int j = 1; j < 32; ++j) mx = fmaxf(mx, s[j]);
    float sum = 0.f;
#pragma unroll
    for (int j = 0; j < 32; ++j) { float e = __expf(s[j] - mx); s[j] = e; sum += e; }
    float inv = 1.0f / sum;
#pragma unroll
    for (int j = 0; j < 32; ++j) hme[j] = s[j] * inv * vv[j];
    float h32[32];
    gemv_f<32, 32>(hme, aW1, h32);
    ln_relu_store_f<32>(h32, ag1, ab1, hme);
    gemv_f<32, 16>(hme, aW2, a16);
#pragma unroll
    for (int j = 0; j < 16; ++j) a16[j] += ab2[j];
  }

  float r16[16];
  {
    gemv128_f(xr, rW1, acc);
#pragma unroll
    for (int j = 0; j < 64; ++j)
      acc[j] = fmaf(p2, rW1[130 * 64 + j], fmaf(p1, rW1[129 * 64 + j], fmaf(p0, rW1[128 * 64 + j], acc[j])));
    ln_relu_store_f<64>(acc, rg1, rb1, hme);
    float r32[32];
    gemv_f<64, 32>(hme, rW2, r32);
    ln_relu_store_f<32>(r32, rg2, rb2, hme);
    gemv_f<32, 16>(hme, rW3, r16);
#pragma unroll
    for (int j = 0; j < 16; ++j) r16[j] += rb3[j];
  }

#pragma unroll
  for (int j = 0; j < 16; ++j) hme[j] = a16[j];
#pragma unroll
  for (int j = 0; j < 16; ++j) hme[16 + j] = r16[j];
  {
    float f16v[16], hg[16], o3[3];
    gemv_f<32, 16>(hme, gW1, f16v);
    ln_relu_store_f<16>(f16v, gg1, gb1, hg);
    gemv_f<16, 3>(hg, gW2, o3);
#pragma unroll
    for (int c = 0; c < 3; ++c) out[row * 3 + c] = o3[c] + gb2[c];
  }
}

// ---------- launch ----------

extern "C" void kernel_launch(void* const* d_in, const int* in_sizes, int n_in,
                              void* d_out, int out_size, void* d_ws, size_t ws_size,
                              hipStream_t stream) {
  const float* rep = (const float*)d_in[0];
  const float* par = (const float*)d_in[1];
  const float* kW1 = (const float*)d_in[2];
  const float* kg1 = (const float*)d_in[3];
  const float* kb1 = (const float*)d_in[4];
  const float* kW2 = (const float*)d_in[5];
  const float* kb2 = (const float*)d_in[6];
  const float* qW1 = (const float*)d_in[7];
  const float* qg1 = (const float*)d_in[8];
  const float* qb1 = (const float*)d_in[9];
  const float* qW2 = (const float*)d_in[10];
  const float* qb2 = (const float*)d_in[11];
  const float* vW1 = (const float*)d_in[12];
  const float* vg1 = (const float*)d_in[13];
  const float* vb1 = (const float*)d_in[14];
  const float* vW2 = (const float*)d_in[15];
  const float* vb2 = (const float*)d_in[16];
  const float* aW1 = (const float*)d_in[17];
  const float* ag1 = (const float*)d_in[18];
  const float* ab1 = (const float*)d_in[19];
  const float* aW2 = (const float*)d_in[20];
  const float* ab2 = (const float*)d_in[21];
  const float* rW1 = (const float*)d_in[22];
  const float* rg1 = (const float*)d_in[23];
  const float* rb1 = (const float*)d_in[24];
  const float* rW2 = (const float*)d_in[25];
  const float* rg2 = (const float*)d_in[26];
  const float* rb2 = (const float*)d_in[27];
  const float* rW3 = (const float*)d_in[28];
  const float* rb3 = (const float*)d_in[29];
  const float* gW1 = (const float*)d_in[30];
  const float* gg1 = (const float*)d_in[31];
  const float* gb1 = (const float*)d_in[32];
  const float* gW2 = (const float*)d_in[33];
  const float* gb2 = (const float*)d_in[34];

  const int N = in_sizes[0] / 128;
  float* out = (float*)d_out;

  if (ws_size >= (size_t)WS_U32_TOTAL * 4) {
    unsigned* ws = (unsigned*)d_ws;
    prepack_kernel<<<34, 256, 0, stream>>>(kW1, vW1, rW1, kW2, vW2, rW2,
                                           aW1, aW2, rW3, gW1, qW2, ws);
    const int grid = (N + BLK - 1) / BLK;
    approach_fused_pk_kernel<<<grid, BLK, 0, stream>>>(
        rep, par, ws,
        kg1, kb1, kb2,
        qW1, qg1, qb1, qb2,
        vg1, vb1, vb2,
        ag1, ab1, ab2,
        rW1, rg1, rb1, rg2, rb2, rb3,
        gg1, gb1, gW2, gb2,
        out, N);
  } else {
    const int grid = (N + 63) / 64;
    approach_fused_f32_kernel<<<grid, 64, 0, stream>>>(
        rep, par,
        kW1, kg1, kb1, kW2, kb2,
        qW1, qg1, qb1, qW2, qb2,
        vW1, vg1, vb1, vW2, vb2,
        aW1, ag1, ab1, aW2, ab2,
        rW1, rg1, rb1, rW2, rg2, rb2, rW3, rb3,
        gW1, gg1, gb1, gW2, gb2,
        out, N);
  }
}

// Round 3
// 500.129 us; speedup vs baseline: 3.6633x; 2.4153x over previous
//
#include <hip/hip_runtime.h>
#include <math.h>

#define LN_EPS 1e-5f
#define NWAVE 8
#define TPB 512
#define ROWS_PER_BLOCK 256   // 8 waves x 32 rows
#define HSTRIDE 152          // halves; 304B row stride: 16B-aligned, ~2-way banks

typedef _Float16 half8 __attribute__((ext_vector_type(8)));
typedef float f32x4 __attribute__((ext_vector_type(4)));

// weight-LDS segment offsets (in halves); each fragment = 512 halves (64 lanes x 8)
#define OFF_W1   0        // [128x192] = kW1|vW1|rW1[0:128], KB=4, CB=12 -> 48 frags
#define OFF_KW2  24576    // [64x32] KB=2 CB=2 -> 4 frags
#define OFF_VW2  26624
#define OFF_RW2  28672
#define OFF_QW2  30720    // [16->pad32 x 32] KB=1 CB=2 -> 2 frags (rows 16-31 zero)
#define OFF_AW1  31744    // [32x32] KB=1 CB=2
#define OFF_AW2  32768    // [32x16] KB=1 CB=1
#define OFF_RW3  33280
#define OFF_GW1  33792
#define OFF_GW2  34304    // [16->pad32 x 3->pad16] zeros outside valid region
#define WL_HALVES 34816

__device__ __forceinline__ f32x4 mfma16(half8 a, half8 b, f32x4 c) {
  return __builtin_amdgcn_mfma_f32_16x16x32_f16(a, b, c, 0, 0, 0);
}

// Stage fp32 [K][N] row-major weight into B-fragment order (coalesced source reads):
// element (k,c) -> frag (cb*KBdst + k/32), lane ((k>>3)&3)*16 + (c&15), elem k&7
__device__ __forceinline__ void stage_frag(const float* __restrict__ W,
    int Ksrc, int Nsrc, int Kpad, int Npad, int KBdst, int cb_off,
    _Float16* __restrict__ wl, int off, int tid) {
  int tot = Kpad * Npad;
  for (int idx = tid; idx < tot; idx += TPB) {
    int k = idx / Npad;
    int c = idx - k * Npad;
    float v = (k < Ksrc && c < Nsrc) ? W[k * Nsrc + c] : 0.f;
    int cb = cb_off + (c >> 4);
    int lanei = ((k >> 3) & 3) * 16 + (c & 15);
    int dst = off + ((cb * KBdst + (k >> 5)) * 64 + lanei) * 8 + (k & 7);
    wl[dst] = (_Float16)v;
  }
}

__global__ __launch_bounds__(TPB, 2)
void approach_mfma_kernel(
    const float* __restrict__ rep, const float* __restrict__ par,
    const float* __restrict__ kW1, const float* __restrict__ kg1, const float* __restrict__ kb1,
    const float* __restrict__ kW2, const float* __restrict__ kb2,
    const float* __restrict__ qW1, const float* __restrict__ qg1, const float* __restrict__ qb1,
    const float* __restrict__ qW2, const float* __restrict__ qb2,
    const float* __restrict__ vW1, const float* __restrict__ vg1, const float* __restrict__ vb1,
    const float* __restrict__ vW2, const float* __restrict__ vb2,
    const float* __restrict__ aW1, const float* __restrict__ ag1, const float* __restrict__ ab1,
    const float* __restrict__ aW2, const float* __restrict__ ab2,
    const float* __restrict__ rW1, const float* __restrict__ rg1, const float* __restrict__ rb1,
    const float* __restrict__ rW2, const float* __restrict__ rg2, const float* __restrict__ rb2,
    const float* __restrict__ rW3, const float* __restrict__ rb3,
    const float* __restrict__ gW1, const float* __restrict__ gg1, const float* __restrict__ gb1,
    const float* __restrict__ gW2, const float* __restrict__ gb2,
    float* __restrict__ out, int N)
{
  __shared__ __align__(16) _Float16 wl[WL_HALVES];
  __shared__ __align__(16) _Float16 hs[NWAVE][32][HSTRIDE];

  const int tid = threadIdx.x;

  // ---- stage all weights into fragment-ordered LDS (once per block)
  stage_frag(kW1, 128, 64, 128, 64, 4, 0, wl, OFF_W1, tid);
  stage_frag(vW1, 128, 64, 128, 64, 4, 4, wl, OFF_W1, tid);
  stage_frag(rW1, 128, 64, 128, 64, 4, 8, wl, OFF_W1, tid);  // rows 0..127
  stage_frag(kW2, 64, 32, 64, 32, 2, 0, wl, OFF_KW2, tid);
  stage_frag(vW2, 64, 32, 64, 32, 2, 0, wl, OFF_VW2, tid);
  stage_frag(rW2, 64, 32, 64, 32, 2, 0, wl, OFF_RW2, tid);
  stage_frag(qW2, 16, 32, 32, 32, 1, 0, wl, OFF_QW2, tid);
  stage_frag(aW1, 32, 32, 32, 32, 1, 0, wl, OFF_AW1, tid);
  stage_frag(aW2, 32, 16, 32, 16, 1, 0, wl, OFF_AW2, tid);
  stage_frag(rW3, 32, 16, 32, 16, 1, 0, wl, OFF_RW3, tid);
  stage_frag(gW1, 32, 16, 32, 16, 1, 0, wl, OFF_GW1, tid);
  stage_frag(gW2, 16, 3, 32, 16, 1, 0, wl, OFF_GW2, tid);
  __syncthreads();

  const int wave = tid >> 6;
  const int lane = tid & 63;
  const int lo = lane & 15;     // A-row / D-col / B-col index
  const int g4 = lane >> 4;     // k-subblock / D-row group
  const long long rb0 = (long long)blockIdx.x * ROWS_PER_BLOCK + wave * 32;
  if (rb0 + 32 > N) return;

  _Float16* hw = &hs[wave][0][0];  // [32][HSTRIDE]

  // B-fragment load from weight LDS
  auto ldb = [&](int off, int frag) -> half8 {
    return *reinterpret_cast<const half8*>(&wl[off + frag * 512 + lane * 8]);
  };
  // A-fragment load from per-wave h scratch (f16, row = t*16+lo, k = kb*32+g4*8)
  auto lda = [&](int t, int kb) -> half8 {
    return *reinterpret_cast<const half8*>(&hw[(t * 16 + lo) * HSTRIDE + kb * 32 + g4 * 8]);
  };
  const f32x4 z4 = {0.f, 0.f, 0.f, 0.f};

  // ---- x A-fragments: rows rb0 + t*16 + lo, k = kb*32 + g4*8 + j
  half8 xa[2][4];
#pragma unroll
  for (int t = 0; t < 2; ++t) {
    const float* xr = rep + (size_t)(rb0 + t * 16 + lo) * 128 + g4 * 8;
#pragma unroll
    for (int kb = 0; kb < 4; ++kb) {
      f32x4 u0 = *reinterpret_cast<const f32x4*>(xr + kb * 32);
      f32x4 u1 = *reinterpret_cast<const f32x4*>(xr + kb * 32 + 4);
      half8 h;
#pragma unroll
      for (int j = 0; j < 4; ++j) { h[j] = (_Float16)u0[j]; h[4 + j] = (_Float16)u1[j]; }
      xa[t][kb] = h;
    }
  }

  // LN+ReLU in D-layout, write f16 to h scratch rows t*16 + g4*4 + r, col cb*16+lo
  auto ln_write = [&](const f32x4* acc, int CB, const float* gv, const float* bv, int t) {
#pragma unroll 4
    for (int r = 0; r < 4; ++r) {
      float s = 0.f, q = 0.f;
      for (int cb = 0; cb < CB; ++cb) { float x = acc[cb][r]; s += x; q = fmaf(x, x, q); }
#pragma unroll
      for (int m = 1; m < 16; m <<= 1) { s += __shfl_xor(s, m, 64); q += __shfl_xor(q, m, 64); }
      float inv = 1.f / (16.f * CB);
      float mean = s * inv;
      float var = fmaf(q, inv, -mean * mean);
      float rstd = rsqrtf(var + LN_EPS);
      for (int cb = 0; cb < CB; ++cb) {
        float h = fmaxf(fmaf((acc[cb][r] - mean) * rstd, gv[cb], bv[cb]), 0.f);
        hw[(t * 16 + g4 * 4 + r) * HSTRIDE + cb * 16 + lo] = (_Float16)h;
      }
    }
  };

  f32x4 kk[2][2], vv[2][2], qq[2][2], a16[2], r16[2];

  // ================= key tower =================
  {
    f32x4 acc[2][4];
#pragma unroll
    for (int t = 0; t < 2; ++t)
#pragma unroll
      for (int cb = 0; cb < 4; ++cb) acc[t][cb] = z4;
#pragma unroll
    for (int cb = 0; cb < 4; ++cb)
#pragma unroll
      for (int kb = 0; kb < 4; ++kb) {
        half8 b = ldb(OFF_W1, (0 * 4 + cb) * 4 + kb);
        acc[0][cb] = mfma16(xa[0][kb], b, acc[0][cb]);
        acc[1][cb] = mfma16(xa[1][kb], b, acc[1][cb]);
      }
    float gv[4], bv[4];
#pragma unroll
    for (int cb = 0; cb < 4; ++cb) { gv[cb] = kg1[cb * 16 + lo]; bv[cb] = kb1[cb * 16 + lo]; }
    ln_write(acc[0], 4, gv, bv, 0);
    ln_write(acc[1], 4, gv, bv, 1);
    // layer2: [16x64]@[64x32]
    float biasv[2] = {kb2[lo], kb2[16 + lo]};
#pragma unroll
    for (int t = 0; t < 2; ++t) {
      half8 a0 = lda(t, 0), a1 = lda(t, 1);
#pragma unroll
      for (int cb = 0; cb < 2; ++cb) {
        f32x4 o = mfma16(a0, ldb(OFF_KW2, cb * 2 + 0), z4);
        o = mfma16(a1, ldb(OFF_KW2, cb * 2 + 1), o);
#pragma unroll
        for (int r = 0; r < 4; ++r) o[r] += biasv[cb];
        kk[t][cb] = o;
      }
    }
  }

  // ================= value tower =================
  {
    f32x4 acc[2][4];
#pragma unroll
    for (int t = 0; t < 2; ++t)
#pragma unroll
      for (int cb = 0; cb < 4; ++cb) acc[t][cb] = z4;
#pragma unroll
    for (int cb = 0; cb < 4; ++cb)
#pragma unroll
      for (int kb = 0; kb < 4; ++kb) {
        half8 b = ldb(OFF_W1, (1 * 4 + cb) * 4 + kb);
        acc[0][cb] = mfma16(xa[0][kb], b, acc[0][cb]);
        acc[1][cb] = mfma16(xa[1][kb], b, acc[1][cb]);
      }
    float gv[4], bv[4];
#pragma unroll
    for (int cb = 0; cb < 4; ++cb) { gv[cb] = vg1[cb * 16 + lo]; bv[cb] = vb1[cb * 16 + lo]; }
    ln_write(acc[0], 4, gv, bv, 0);
    ln_write(acc[1], 4, gv, bv, 1);
    float biasv[2] = {vb2[lo], vb2[16 + lo]};
#pragma unroll
    for (int t = 0; t < 2; ++t) {
      half8 a0 = lda(t, 0), a1 = lda(t, 1);
#pragma unroll
      for (int cb = 0; cb < 2; ++cb) {
        f32x4 o = mfma16(a0, ldb(OFF_VW2, cb * 2 + 0), z4);
        o = mfma16(a1, ldb(OFF_VW2, cb * 2 + 1), o);
#pragma unroll
        for (int r = 0; r < 4; ++r) o[r] += biasv[cb];
        vv[t][cb] = o;
      }
    }
  }

  // ---- parameters for r and q towers (D-layout rows)
  float pv[2][4][3];
#pragma unroll
  for (int t = 0; t < 2; ++t)
#pragma unroll
    for (int r = 0; r < 4; ++r) {
      size_t prow = (size_t)(rb0 + t * 16 + g4 * 4 + r) * 3;
#pragma unroll
      for (int i = 0; i < 3; ++i) pv[t][r][i] = par[prow + i];
    }

  // ================= residuals tower =================
  {
    f32x4 acc[2][4];
#pragma unroll
    for (int t = 0; t < 2; ++t)
#pragma unroll
      for (int cb = 0; cb < 4; ++cb) acc[t][cb] = z4;
#pragma unroll
    for (int cb = 0; cb < 4; ++cb)
#pragma unroll
      for (int kb = 0; kb < 4; ++kb) {
        half8 b = ldb(OFF_W1, (2 * 4 + cb) * 4 + kb);
        acc[0][cb] = mfma16(xa[0][kb], b, acc[0][cb]);
        acc[1][cb] = mfma16(xa[1][kb], b, acc[1][cb]);
      }
    // + parameters rows 128..130 of rW1 (D-layout elementwise)
    float rwp[3][4];
#pragma unroll
    for (int i = 0; i < 3; ++i)
#pragma unroll
      for (int cb = 0; cb < 4; ++cb) rwp[i][cb] = rW1[(128 + i) * 64 + cb * 16 + lo];
#pragma unroll
    for (int t = 0; t < 2; ++t)
#pragma unroll
      for (int cb = 0; cb < 4; ++cb)
#pragma unroll
        for (int r = 0; r < 4; ++r) {
          float v = acc[t][cb][r];
          v = fmaf(pv[t][r][0], rwp[0][cb], v);
          v = fmaf(pv[t][r][1], rwp[1][cb], v);
          v = fmaf(pv[t][r][2], rwp[2][cb], v);
          acc[t][cb][r] = v;
        }
    float gv[4], bv[4];
#pragma unroll
    for (int cb = 0; cb < 4; ++cb) { gv[cb] = rg1[cb * 16 + lo]; bv[cb] = rb1[cb * 16 + lo]; }
    ln_write(acc[0], 4, gv, bv, 0);
    ln_write(acc[1], 4, gv, bv, 1);
    // layer2 -> LN32 -> layer3
    float g2v[2] = {rg2[lo], rg2[16 + lo]}, b2v[2] = {rb2[lo], rb2[16 + lo]};
    f32x4 r32[2][2];
#pragma unroll
    for (int t = 0; t < 2; ++t) {
      half8 a0 = lda(t, 0), a1 = lda(t, 1);
#pragma unroll
      for (int cb = 0; cb < 2; ++cb) {
        f32x4 o = mfma16(a0, ldb(OFF_RW2, cb * 2 + 0), z4);
        o = mfma16(a1, ldb(OFF_RW2, cb * 2 + 1), o);
        r32[t][cb] = o;  // no bias before LN
      }
    }
    ln_write(r32[0], 2, g2v, b2v, 0);
    ln_write(r32[1], 2, g2v, b2v, 1);
    float rb3v = rb3[lo];
#pragma unroll
    for (int t = 0; t < 2; ++t) {
      f32x4 o = mfma16(lda(t, 0), ldb(OFF_RW3, 0), z4);
#pragma unroll
      for (int r = 0; r < 4; ++r) o[r] += rb3v;
      r16[t] = o;
    }
  }

  // ================= query tower =================
  {
    float qwv[3] = {qW1[lo], qW1[16 + lo], qW1[32 + lo]};
    float qgv = qg1[lo], qbv = qb1[lo];
#pragma unroll
    for (int t = 0; t < 2; ++t) {
      f32x4 aq;
#pragma unroll
      for (int r = 0; r < 4; ++r) {
        float v = pv[t][r][0] * qwv[0];
        v = fmaf(pv[t][r][1], qwv[1], v);
        v = fmaf(pv[t][r][2], qwv[2], v);
        aq[r] = v;
      }
      ln_write(&aq, 1, &qgv, &qbv, t);
      // zero cols 16..31 so the padded-K A-frag is exactly zero
#pragma unroll
      for (int r = 0; r < 4; ++r)
        hw[(t * 16 + g4 * 4 + r) * HSTRIDE + 16 + lo] = (_Float16)0.f;
    }
    float biasv[2] = {qb2[lo], qb2[16 + lo]};
#pragma unroll
    for (int t = 0; t < 2; ++t) {
      half8 a0 = lda(t, 0);
#pragma unroll
      for (int cb = 0; cb < 2; ++cb) {
        f32x4 o = mfma16(a0, ldb(OFF_QW2, cb), z4);
#pragma unroll
        for (int r = 0; r < 4; ++r) o[r] += biasv[cb];
        qq[t][cb] = o;
      }
    }
  }

  // ================= attention =================
  {
#pragma unroll
    for (int t = 0; t < 2; ++t)
#pragma unroll
      for (int r = 0; r < 4; ++r) {
        float s0 = qq[t][0][r] * kk[t][0][r];
        float s1 = qq[t][1][r] * kk[t][1][r];
        float mx = fmaxf(s0, s1);
#pragma unroll
        for (int m = 1; m < 16; m <<= 1) mx = fmaxf(mx, __shfl_xor(mx, m, 64));
        float e0 = __expf(s0 - mx), e1 = __expf(s1 - mx);
        float sm = e0 + e1;
#pragma unroll
        for (int m = 1; m < 16; m <<= 1) sm += __shfl_xor(sm, m, 64);
        float inv = 1.f / sm;
        hw[(t * 16 + g4 * 4 + r) * HSTRIDE + lo] = (_Float16)(e0 * inv * vv[t][0][r]);
        hw[(t * 16 + g4 * 4 + r) * HSTRIDE + 16 + lo] = (_Float16)(e1 * inv * vv[t][1][r]);
      }
    // att tower: 32 -> 32 (LN,ReLU) -> 16
    float agv[2] = {ag1[lo], ag1[16 + lo]}, abv[2] = {ab1[lo], ab1[16 + lo]};
    f32x4 h32[2][2];
#pragma unroll
    for (int t = 0; t < 2; ++t) {
      half8 a0 = lda(t, 0);
#pragma unroll
      for (int cb = 0; cb < 2; ++cb) h32[t][cb] = mfma16(a0, ldb(OFF_AW1, cb), z4);
    }
    ln_write(h32[0], 2, agv, abv, 0);
    ln_write(h32[1], 2, agv, abv, 1);
    float ab2v = ab2[lo];
#pragma unroll
    for (int t = 0; t < 2; ++t) {
      f32x4 o = mfma16(lda(t, 0), ldb(OFF_AW2, 0), z4);
#pragma unroll
      for (int r = 0; r < 4; ++r) o[r] += ab2v;
      a16[t] = o;
    }
  }

  // ================= get_approach tower =================
  {
    // features = concat(att, residuals): cols 0..15 = a16, 16..31 = r16
#pragma unroll
    for (int t = 0; t < 2; ++t)
#pragma unroll
      for (int r = 0; r < 4; ++r) {
        hw[(t * 16 + g4 * 4 + r) * HSTRIDE + lo] = (_Float16)a16[t][r];
        hw[(t * 16 + g4 * 4 + r) * HSTRIDE + 16 + lo] = (_Float16)r16[t][r];
      }
    float ggv = gg1[lo], gbv = gb1[lo];
    f32x4 f1[2];
#pragma unroll
    for (int t = 0; t < 2; ++t) f1[t] = mfma16(lda(t, 0), ldb(OFF_GW1, 0), z4);
    ln_write(&f1[0], 1, &ggv, &gbv, 0);
    ln_write(&f1[1], 1, &ggv, &gbv, 1);
    // zero cols 16..31 (padded K of gW2) — written region only held features, keep exact
#pragma unroll
    for (int t = 0; t < 2; ++t)
#pragma unroll
      for (int r = 0; r < 4; ++r)
        hw[(t * 16 + g4 * 4 + r) * HSTRIDE + 16 + lo] = (_Float16)0.f;
    float gb2v = (lo < 3) ? gb2[lo] : 0.f;
#pragma unroll
    for (int t = 0; t < 2; ++t) {
      f32x4 o = mfma16(lda(t, 0), ldb(OFF_GW2, 0), z4);
      if (lo < 3) {
#pragma unroll
        for (int r = 0; r < 4; ++r)
          out[(size_t)(rb0 + t * 16 + g4 * 4 + r) * 3 + lo] = o[r] + gb2v;
      }
    }
  }
}

// ---------- launch ----------

extern "C" void kernel_launch(void* const* d_in, const int* in_sizes, int n_in,
                              void* d_out, int out_size, void* d_ws, size_t ws_size,
                              hipStream_t stream) {
  const float* rep = (const float*)d_in[0];
  const float* par = (const float*)d_in[1];
  const float* kW1 = (const float*)d_in[2];
  const float* kg1 = (const float*)d_in[3];
  const float* kb1 = (const float*)d_in[4];
  const float* kW2 = (const float*)d_in[5];
  const float* kb2 = (const float*)d_in[6];
  const float* qW1 = (const float*)d_in[7];
  const float* qg1 = (const float*)d_in[8];
  const float* qb1 = (const float*)d_in[9];
  const float* qW2 = (const float*)d_in[10];
  const float* qb2 = (const float*)d_in[11];
  const float* vW1 = (const float*)d_in[12];
  const float* vg1 = (const float*)d_in[13];
  const float* vb1 = (const float*)d_in[14];
  const float* vW2 = (const float*)d_in[15];
  const float* vb2 = (const float*)d_in[16];
  const float* aW1 = (const float*)d_in[17];
  const float* ag1 = (const float*)d_in[18];
  const float* ab1 = (const float*)d_in[19];
  const float* aW2 = (const float*)d_in[20];
  const float* ab2 = (const float*)d_in[21];
  const float* rW1 = (const float*)d_in[22];
  const float* rg1 = (const float*)d_in[23];
  const float* rb1 = (const float*)d_in[24];
  const float* rW2 = (const float*)d_in[25];
  const float* rg2 = (const float*)d_in[26];
  const float* rb2 = (const float*)d_in[27];
  const float* rW3 = (const float*)d_in[28];
  const float* rb3 = (const float*)d_in[29];
  const float* gW1 = (const float*)d_in[30];
  const float* gg1 = (const float*)d_in[31];
  const float* gb1 = (const float*)d_in[32];
  const float* gW2 = (const float*)d_in[33];
  const float* gb2 = (const float*)d_in[34];

  const int N = in_sizes[0] / 128;
  float* out = (float*)d_out;

  const int grid = (N + ROWS_PER_BLOCK - 1) / ROWS_PER_BLOCK;
  approach_mfma_kernel<<<grid, TPB, 0, stream>>>(
      rep, par,
      kW1, kg1, kb1, kW2, kb2,
      qW1, qg1, qb1, qW2, qb2,
      vW1, vg1, vb1, vW2, vb2,
      aW1, ag1, ab1, aW2, ab2,
      rW1, rg1, rb1, rW2, rg2, rb2, rW3, rb3,
      gW1, gg1, gb1, gW2, gb2,
      out, N);
}

// Round 4
// 349.104 us; speedup vs baseline: 5.2480x; 1.4326x over previous
//
#include <hip/hip_runtime.h>
#include <math.h>

#define LN_EPS 1e-5f
#define NWAVE 8
#define TPB 512
#define ROWS_PER_BLOCK 256   // 8 waves x 32 rows
#define HSTRIDE 72           // halves; 144B row stride (16B-aligned)

typedef _Float16 half8 __attribute__((ext_vector_type(8)));
typedef float f32x4 __attribute__((ext_vector_type(4)));

// weight-fragment table offsets (in halves); each fragment = 512 halves (64 lanes x 8)
#define OFF_W1   0        // [128x192] = kW1|vW1|rW1[0:128], KB=4, CB=12 -> 48 frags
#define OFF_KW2  24576    // [64x32] KB=2 CB=2 -> 4 frags
#define OFF_VW2  26624
#define OFF_RW2  28672
#define OFF_QW2  30720    // [16->pad32 x 32] KB=1 CB=2 -> 2 frags (rows 16-31 zero)
#define OFF_AW1  31744    // [32x32] KB=1 CB=2
#define OFF_AW2  32768    // [32x16] KB=1 CB=1
#define OFF_RW3  33280
#define OFF_GW1  33792
#define OFF_GW2  34304    // [16->pad32 x 3->pad16] zeros outside valid region
#define WL_HALVES 34816

// module-scope weight-fragment table (global memory, L2-resident, 68 KB)
__device__ _Float16 g_wfrag[WL_HALVES];

__device__ __forceinline__ f32x4 mfma16(half8 a, half8 b, f32x4 c) {
  return __builtin_amdgcn_mfma_f32_16x16x32_f16(a, b, c, 0, 0, 0);
}

// fp32 [K][N] row-major weight -> B-fragment order:
// element (k,c) -> frag (cb*KBdst + k/32), lane ((k>>3)&3)*16 + (c&15), elem k&7
__device__ __forceinline__ void pack_frag(const float* __restrict__ W,
    int Ksrc, int Nsrc, int Kpad, int Npad, int KBdst, int cb_off,
    int off, int gtid, int gstride) {
  int tot = Kpad * Npad;
  for (int idx = gtid; idx < tot; idx += gstride) {
    int k = idx / Npad;
    int c = idx - k * Npad;
    float v = (k < Ksrc && c < Nsrc) ? W[k * Nsrc + c] : 0.f;
    int cb = cb_off + (c >> 4);
    int lanei = ((k >> 3) & 3) * 16 + (c & 15);
    int dst = off + ((cb * KBdst + (k >> 5)) * 64 + lanei) * 8 + (k & 7);
    g_wfrag[dst] = (_Float16)v;
  }
}

__global__ void prepack_kernel(const float* kW1, const float* vW1, const float* rW1,
                               const float* kW2, const float* vW2, const float* rW2,
                               const float* qW2, const float* aW1, const float* aW2,
                               const float* rW3, const float* gW1, const float* gW2) {
  int gtid = blockIdx.x * blockDim.x + threadIdx.x;
  int gstride = gridDim.x * blockDim.x;
  pack_frag(kW1, 128, 64, 128, 64, 4, 0, OFF_W1, gtid, gstride);
  pack_frag(vW1, 128, 64, 128, 64, 4, 4, OFF_W1, gtid, gstride);
  pack_frag(rW1, 128, 64, 128, 64, 4, 8, OFF_W1, gtid, gstride);  // rows 0..127
  pack_frag(kW2, 64, 32, 64, 32, 2, 0, OFF_KW2, gtid, gstride);
  pack_frag(vW2, 64, 32, 64, 32, 2, 0, OFF_VW2, gtid, gstride);
  pack_frag(rW2, 64, 32, 64, 32, 2, 0, OFF_RW2, gtid, gstride);
  pack_frag(qW2, 16, 32, 32, 32, 1, 0, OFF_QW2, gtid, gstride);
  pack_frag(aW1, 32, 32, 32, 32, 1, 0, OFF_AW1, gtid, gstride);
  pack_frag(aW2, 32, 16, 32, 16, 1, 0, OFF_AW2, gtid, gstride);
  pack_frag(rW3, 32, 16, 32, 16, 1, 0, OFF_RW3, gtid, gstride);
  pack_frag(gW1, 32, 16, 32, 16, 1, 0, OFF_GW1, gtid, gstride);
  pack_frag(gW2, 16, 3, 32, 16, 1, 0, OFF_GW2, gtid, gstride);
}

__global__ __launch_bounds__(TPB, 4)
void approach_mfma_kernel(
    const float* __restrict__ rep, const float* __restrict__ par,
    const float* __restrict__ kg1, const float* __restrict__ kb1, const float* __restrict__ kb2,
    const float* __restrict__ qW1, const float* __restrict__ qg1, const float* __restrict__ qb1,
    const float* __restrict__ qb2,
    const float* __restrict__ vg1, const float* __restrict__ vb1, const float* __restrict__ vb2,
    const float* __restrict__ ag1, const float* __restrict__ ab1, const float* __restrict__ ab2,
    const float* __restrict__ rW1, const float* __restrict__ rg1, const float* __restrict__ rb1,
    const float* __restrict__ rg2, const float* __restrict__ rb2, const float* __restrict__ rb3,
    const float* __restrict__ gg1, const float* __restrict__ gb1, const float* __restrict__ gb2,
    float* __restrict__ out, int N)
{
  __shared__ __align__(16) _Float16 hs[NWAVE][32][HSTRIDE];

  const int tid = threadIdx.x;
  const int wave = tid >> 6;
  const int lane = tid & 63;
  const int lo = lane & 15;     // A-row / D-col / B-col index
  const int g4 = lane >> 4;     // k-subblock / D-row group
  const long long rb0 = (long long)blockIdx.x * ROWS_PER_BLOCK + wave * 32;
  if (rb0 + 32 > N) return;

  _Float16* hw = &hs[wave][0][0];  // [32][HSTRIDE]

  // B-fragment load from global weight table (L2-hot, coalesced 16B/lane)
  auto ldb = [&](int off, int frag) -> half8 {
    return *reinterpret_cast<const half8*>(&g_wfrag[off + frag * 512 + lane * 8]);
  };
  // A-fragment load from per-wave h scratch (f16, row = t*16+lo, k = kb*32+g4*8)
  auto lda = [&](int t, int kb) -> half8 {
    return *reinterpret_cast<const half8*>(&hw[(t * 16 + lo) * HSTRIDE + kb * 32 + g4 * 8]);
  };
  const f32x4 z4 = {0.f, 0.f, 0.f, 0.f};

  // ---- x A-fragments: rows rb0 + t*16 + lo, k = kb*32 + g4*8 + j
  half8 xa[2][4];
#pragma unroll
  for (int t = 0; t < 2; ++t) {
    const float* xr = rep + (size_t)(rb0 + t * 16 + lo) * 128 + g4 * 8;
#pragma unroll
    for (int kb = 0; kb < 4; ++kb) {
      f32x4 u0 = *reinterpret_cast<const f32x4*>(xr + kb * 32);
      f32x4 u1 = *reinterpret_cast<const f32x4*>(xr + kb * 32 + 4);
      half8 h;
#pragma unroll
      for (int j = 0; j < 4; ++j) { h[j] = (_Float16)u0[j]; h[4 + j] = (_Float16)u1[j]; }
      xa[t][kb] = h;
    }
  }

  // LN+ReLU in D-layout, write f16 to h scratch rows t*16 + g4*4 + r, col cb*16+lo
  auto ln_write = [&](const f32x4* acc, int CB, const float* gv, const float* bv, int t) {
#pragma unroll 4
    for (int r = 0; r < 4; ++r) {
      float s = 0.f, q = 0.f;
      for (int cb = 0; cb < CB; ++cb) { float x = acc[cb][r]; s += x; q = fmaf(x, x, q); }
#pragma unroll
      for (int m = 1; m < 16; m <<= 1) { s += __shfl_xor(s, m, 64); q += __shfl_xor(q, m, 64); }
      float inv = 1.f / (16.f * CB);
      float mean = s * inv;
      float var = fmaf(q, inv, -mean * mean);
      float rstd = rsqrtf(var + LN_EPS);
      for (int cb = 0; cb < CB; ++cb) {
        float h = fmaxf(fmaf((acc[cb][r] - mean) * rstd, gv[cb], bv[cb]), 0.f);
        hw[(t * 16 + g4 * 4 + r) * HSTRIDE + cb * 16 + lo] = (_Float16)h;
      }
    }
  };

  f32x4 kk[2][2], vv[2][2], qq[2][2], a16[2], r16[2];

  // ================= key tower =================
  {
    f32x4 acc[2][4];
#pragma unroll
    for (int t = 0; t < 2; ++t)
#pragma unroll
      for (int cb = 0; cb < 4; ++cb) acc[t][cb] = z4;
#pragma unroll
    for (int cb = 0; cb < 4; ++cb)
#pragma unroll
      for (int kb = 0; kb < 4; ++kb) {
        half8 b = ldb(OFF_W1, (0 * 4 + cb) * 4 + kb);
        acc[0][cb] = mfma16(xa[0][kb], b, acc[0][cb]);
        acc[1][cb] = mfma16(xa[1][kb], b, acc[1][cb]);
      }
    float gv[4], bv[4];
#pragma unroll
    for (int cb = 0; cb < 4; ++cb) { gv[cb] = kg1[cb * 16 + lo]; bv[cb] = kb1[cb * 16 + lo]; }
    ln_write(acc[0], 4, gv, bv, 0);
    ln_write(acc[1], 4, gv, bv, 1);
    float biasv[2] = {kb2[lo], kb2[16 + lo]};
#pragma unroll
    for (int t = 0; t < 2; ++t) {
      half8 a0 = lda(t, 0), a1 = lda(t, 1);
#pragma unroll
      for (int cb = 0; cb < 2; ++cb) {
        f32x4 o = mfma16(a0, ldb(OFF_KW2, cb * 2 + 0), z4);
        o = mfma16(a1, ldb(OFF_KW2, cb * 2 + 1), o);
#pragma unroll
        for (int r = 0; r < 4; ++r) o[r] += biasv[cb];
        kk[t][cb] = o;
      }
    }
  }

  // ================= value tower =================
  {
    f32x4 acc[2][4];
#pragma unroll
    for (int t = 0; t < 2; ++t)
#pragma unroll
      for (int cb = 0; cb < 4; ++cb) acc[t][cb] = z4;
#pragma unroll
    for (int cb = 0; cb < 4; ++cb)
#pragma unroll
      for (int kb = 0; kb < 4; ++kb) {
        half8 b = ldb(OFF_W1, (1 * 4 + cb) * 4 + kb);
        acc[0][cb] = mfma16(xa[0][kb], b, acc[0][cb]);
        acc[1][cb] = mfma16(xa[1][kb], b, acc[1][cb]);
      }
    float gv[4], bv[4];
#pragma unroll
    for (int cb = 0; cb < 4; ++cb) { gv[cb] = vg1[cb * 16 + lo]; bv[cb] = vb1[cb * 16 + lo]; }
    ln_write(acc[0], 4, gv, bv, 0);
    ln_write(acc[1], 4, gv, bv, 1);
    float biasv[2] = {vb2[lo], vb2[16 + lo]};
#pragma unroll
    for (int t = 0; t < 2; ++t) {
      half8 a0 = lda(t, 0), a1 = lda(t, 1);
#pragma unroll
      for (int cb = 0; cb < 2; ++cb) {
        f32x4 o = mfma16(a0, ldb(OFF_VW2, cb * 2 + 0), z4);
        o = mfma16(a1, ldb(OFF_VW2, cb * 2 + 1), o);
#pragma unroll
        for (int r = 0; r < 4; ++r) o[r] += biasv[cb];
        vv[t][cb] = o;
      }
    }
  }

  // ---- parameters for r and q towers (D-layout rows)
  float pv[2][4][3];
#pragma unroll
  for (int t = 0; t < 2; ++t)
#pragma unroll
    for (int r = 0; r < 4; ++r) {
      size_t prow = (size_t)(rb0 + t * 16 + g4 * 4 + r) * 3;
#pragma unroll
      for (int i = 0; i < 3; ++i) pv[t][r][i] = par[prow + i];
    }

  // ================= residuals tower =================
  {
    f32x4 acc[2][4];
#pragma unroll
    for (int t = 0; t < 2; ++t)
#pragma unroll
      for (int cb = 0; cb < 4; ++cb) acc[t][cb] = z4;
#pragma unroll
    for (int cb = 0; cb < 4; ++cb)
#pragma unroll
      for (int kb = 0; kb < 4; ++kb) {
        half8 b = ldb(OFF_W1, (2 * 4 + cb) * 4 + kb);
        acc[0][cb] = mfma16(xa[0][kb], b, acc[0][cb]);
        acc[1][cb] = mfma16(xa[1][kb], b, acc[1][cb]);
      }
    float rwp[3][4];
#pragma unroll
    for (int i = 0; i < 3; ++i)
#pragma unroll
      for (int cb = 0; cb < 4; ++cb) rwp[i][cb] = rW1[(128 + i) * 64 + cb * 16 + lo];
#pragma unroll
    for (int t = 0; t < 2; ++t)
#pragma unroll
      for (int cb = 0; cb < 4; ++cb)
#pragma unroll
        for (int r = 0; r < 4; ++r) {
          float v = acc[t][cb][r];
          v = fmaf(pv[t][r][0], rwp[0][cb], v);
          v = fmaf(pv[t][r][1], rwp[1][cb], v);
          v = fmaf(pv[t][r][2], rwp[2][cb], v);
          acc[t][cb][r] = v;
        }
    float gv[4], bv[4];
#pragma unroll
    for (int cb = 0; cb < 4; ++cb) { gv[cb] = rg1[cb * 16 + lo]; bv[cb] = rb1[cb * 16 + lo]; }
    ln_write(acc[0], 4, gv, bv, 0);
    ln_write(acc[1], 4, gv, bv, 1);
    float g2v[2] = {rg2[lo], rg2[16 + lo]}, b2v[2] = {rb2[lo], rb2[16 + lo]};
    f32x4 r32[2][2];
#pragma unroll
    for (int t = 0; t < 2; ++t) {
      half8 a0 = lda(t, 0), a1 = lda(t, 1);
#pragma unroll
      for (int cb = 0; cb < 2; ++cb) {
        f32x4 o = mfma16(a0, ldb(OFF_RW2, cb * 2 + 0), z4);
        o = mfma16(a1, ldb(OFF_RW2, cb * 2 + 1), o);
        r32[t][cb] = o;  // no bias before LN
      }
    }
    ln_write(r32[0], 2, g2v, b2v, 0);
    ln_write(r32[1], 2, g2v, b2v, 1);
    float rb3v = rb3[lo];
#pragma unroll
    for (int t = 0; t < 2; ++t) {
      f32x4 o = mfma16(lda(t, 0), ldb(OFF_RW3, 0), z4);
#pragma unroll
      for (int r = 0; r < 4; ++r) o[r] += rb3v;
      r16[t] = o;
    }
  }

  // ================= query tower =================
  {
    float qwv[3] = {qW1[lo], qW1[16 + lo], qW1[32 + lo]};
    float qgv = qg1[lo], qbv = qb1[lo];
#pragma unroll
    for (int t = 0; t < 2; ++t) {
      f32x4 aq;
#pragma unroll
      for (int r = 0; r < 4; ++r) {
        float v = pv[t][r][0] * qwv[0];
        v = fmaf(pv[t][r][1], qwv[1], v);
        v = fmaf(pv[t][r][2], qwv[2], v);
        aq[r] = v;
      }
      ln_write(&aq, 1, &qgv, &qbv, t);
#pragma unroll
      for (int r = 0; r < 4; ++r)
        hw[(t * 16 + g4 * 4 + r) * HSTRIDE + 16 + lo] = (_Float16)0.f;
    }
    float biasv[2] = {qb2[lo], qb2[16 + lo]};
#pragma unroll
    for (int t = 0; t < 2; ++t) {
      half8 a0 = lda(t, 0);
#pragma unroll
      for (int cb = 0; cb < 2; ++cb) {
        f32x4 o = mfma16(a0, ldb(OFF_QW2, cb), z4);
#pragma unroll
        for (int r = 0; r < 4; ++r) o[r] += biasv[cb];
        qq[t][cb] = o;
      }
    }
  }

  // ================= attention =================
  {
#pragma unroll
    for (int t = 0; t < 2; ++t)
#pragma unroll
      for (int r = 0; r < 4; ++r) {
        float s0 = qq[t][0][r] * kk[t][0][r];
        float s1 = qq[t][1][r] * kk[t][1][r];
        float mx = fmaxf(s0, s1);
#pragma unroll
        for (int m = 1; m < 16; m <<= 1) mx = fmaxf(mx, __shfl_xor(mx, m, 64));
        float e0 = __expf(s0 - mx), e1 = __expf(s1 - mx);
        float sm = e0 + e1;
#pragma unroll
        for (int m = 1; m < 16; m <<= 1) sm += __shfl_xor(sm, m, 64);
        float inv = 1.f / sm;
        hw[(t * 16 + g4 * 4 + r) * HSTRIDE + lo] = (_Float16)(e0 * inv * vv[t][0][r]);
        hw[(t * 16 + g4 * 4 + r) * HSTRIDE + 16 + lo] = (_Float16)(e1 * inv * vv[t][1][r]);
      }
    float agv[2] = {ag1[lo], ag1[16 + lo]}, abv[2] = {ab1[lo], ab1[16 + lo]};
    f32x4 h32[2][2];
#pragma unroll
    for (int t = 0; t < 2; ++t) {
      half8 a0 = lda(t, 0);
#pragma unroll
      for (int cb = 0; cb < 2; ++cb) h32[t][cb] = mfma16(a0, ldb(OFF_AW1, cb), z4);
    }
    ln_write(h32[0], 2, agv, abv, 0);
    ln_write(h32[1], 2, agv, abv, 1);
    float ab2v = ab2[lo];
#pragma unroll
    for (int t = 0; t < 2; ++t) {
      f32x4 o = mfma16(lda(t, 0), ldb(OFF_AW2, 0), z4);
#pragma unroll
      for (int r = 0; r < 4; ++r) o[r] += ab2v;
      a16[t] = o;
    }
  }

  // ================= get_approach tower =================
  {
#pragma unroll
    for (int t = 0; t < 2; ++t)
#pragma unroll
      for (int r = 0; r < 4; ++r) {
        hw[(t * 16 + g4 * 4 + r) * HSTRIDE + lo] = (_Float16)a16[t][r];
        hw[(t * 16 + g4 * 4 + r) * HSTRIDE + 16 + lo] = (_Float16)r16[t][r];
      }
    float ggv = gg1[lo], gbv = gb1[lo];
    f32x4 f1[2];
#pragma unroll
    for (int t = 0; t < 2; ++t) f1[t] = mfma16(lda(t, 0), ldb(OFF_GW1, 0), z4);
    ln_write(&f1[0], 1, &ggv, &gbv, 0);
    ln_write(&f1[1], 1, &ggv, &gbv, 1);
#pragma unroll
    for (int t = 0; t < 2; ++t)
#pragma unroll
      for (int r = 0; r < 4; ++r)
        hw[(t * 16 + g4 * 4 + r) * HSTRIDE + 16 + lo] = (_Float16)0.f;
    float gb2v = (lo < 3) ? gb2[lo] : 0.f;
#pragma unroll
    for (int t = 0; t < 2; ++t) {
      f32x4 o = mfma16(lda(t, 0), ldb(OFF_GW2, 0), z4);
      if (lo < 3) {
#pragma unroll
        for (int r = 0; r < 4; ++r)
          out[(size_t)(rb0 + t * 16 + g4 * 4 + r) * 3 + lo] = o[r] + gb2v;
      }
    }
  }
}

// ---------- launch ----------

extern "C" void kernel_launch(void* const* d_in, const int* in_sizes, int n_in,
                              void* d_out, int out_size, void* d_ws, size_t ws_size,
                              hipStream_t stream) {
  const float* rep = (const float*)d_in[0];
  const float* par = (const float*)d_in[1];
  const float* kW1 = (const float*)d_in[2];
  const float* kg1 = (const float*)d_in[3];
  const float* kb1 = (const float*)d_in[4];
  const float* kW2 = (const float*)d_in[5];
  const float* kb2 = (const float*)d_in[6];
  const float* qW1 = (const float*)d_in[7];
  const float* qg1 = (const float*)d_in[8];
  const float* qb1 = (const float*)d_in[9];
  const float* qW2 = (const float*)d_in[10];
  const float* qb2 = (const float*)d_in[11];
  const float* vW1 = (const float*)d_in[12];
  const float* vg1 = (const float*)d_in[13];
  const float* vb1 = (const float*)d_in[14];
  const float* vW2 = (const float*)d_in[15];
  const float* vb2 = (const float*)d_in[16];
  const float* aW1 = (const float*)d_in[17];
  const float* ag1 = (const float*)d_in[18];
  const float* ab1 = (const float*)d_in[19];
  const float* aW2 = (const float*)d_in[20];
  const float* ab2 = (const float*)d_in[21];
  const float* rW1 = (const float*)d_in[22];
  const float* rg1 = (const float*)d_in[23];
  const float* rb1 = (const float*)d_in[24];
  const float* rW2 = (const float*)d_in[25];
  const float* rg2 = (const float*)d_in[26];
  const float* rb2 = (const float*)d_in[27];
  const float* rW3 = (const float*)d_in[28];
  const float* rb3 = (const float*)d_in[29];
  const float* gW1 = (const float*)d_in[30];
  const float* gg1 = (const float*)d_in[31];
  const float* gb1 = (const float*)d_in[32];
  const float* gW2 = (const float*)d_in[33];
  const float* gb2 = (const float*)d_in[34];

  const int N = in_sizes[0] / 128;
  float* out = (float*)d_out;

  prepack_kernel<<<34, 256, 0, stream>>>(kW1, vW1, rW1, kW2, vW2, rW2,
                                         qW2, aW1, aW2, rW3, gW1, gW2);

  const int grid = (N + ROWS_PER_BLOCK - 1) / ROWS_PER_BLOCK;
  approach_mfma_kernel<<<grid, TPB, 0, stream>>>(
      rep, par,
      kg1, kb1, kb2,
      qW1, qg1, qb1, qb2,
      vg1, vb1, vb2,
      ag1, ab1, ab2,
      rW1, rg1, rb1, rg2, rb2, rb3,
      gg1, gb1, gb2,
      out, N);
}